// Round 10
// baseline (98.915 us; speedup 1.0000x reference)
//
#include <hip/hip_runtime.h>

#define H 1024
#define V 128000
#define NBLK_GATES 768     // 768 blocks * 4 waves = 3072 wave-pairs (rows r, r+3072)
#define NBLK_LOGITS 2000   // 2000 blocks * 4 waves * 16 rows = 128000

typedef float f32x4 __attribute__((ext_vector_type(4)));

// ws float layout:
//  [0,3072)      gi  (r,z,n)
//  [3072,6144)   gh  (r,z,n)
//  [6144,10144)  2000 partial (m,s) pairs from logits blocks
#define WS_GI   0
#define WS_GH   3072
#define WS_PART 6144

__device__ __forceinline__ void online_combine(float& m, float& s, float om, float os) {
    const float M = fmaxf(m, om);
    s = s * __expf(m - M) + os * __expf(om - M);
    m = M;
}

// Dual-row gates (R8 version — 97.6 µs bench): wave w handles row w
// (w_ih @ relu(emb[idx])) and row w+3072 (w_hh @ h), interleaved.
__global__ void __launch_bounds__(256) gates_kernel(
        const int* __restrict__ seq,
        const float* __restrict__ hidden,
        const float* __restrict__ emb,
        const float* __restrict__ w_ih,
        const float* __restrict__ w_hh,
        const float* __restrict__ b_ih,
        const float* __restrict__ b_hh,
        float* __restrict__ ws) {
    const int wid  = threadIdx.x >> 6;
    const int lane = threadIdx.x & 63;
    const int rA   = blockIdx.x * 4 + wid;       // 0..3071
    const int idx  = seq[0];

    const float* wrA = w_ih + (size_t)rA * H;
    const float* wrB = w_hh + (size_t)rA * H;
    const float* vA  = emb + (size_t)idx * H;
    const float* vB  = hidden;

    float accA = 0.f, accB = 0.f;
    #pragma unroll
    for (int k = 0; k < 4; ++k) {
        const int j = lane * 4 + k * 256;
        f32x4 wa = __builtin_nontemporal_load((const f32x4*)(wrA + j));
        f32x4 wb = __builtin_nontemporal_load((const f32x4*)(wrB + j));
        float4 va = *(const float4*)(vA + j);
        float4 vb = *(const float4*)(vB + j);
        va.x = fmaxf(va.x, 0.f); va.y = fmaxf(va.y, 0.f);
        va.z = fmaxf(va.z, 0.f); va.w = fmaxf(va.w, 0.f);
        accA += wa.x * va.x + wa.y * va.y + wa.z * va.z + wa.w * va.w;
        accB += wb.x * vb.x + wb.y * vb.y + wb.z * vb.z + wb.w * vb.w;
    }
    #pragma unroll
    for (int d = 32; d >= 1; d >>= 1) {
        accA += __shfl_xor(accA, d);
        accB += __shfl_xor(accB, d);
    }
    if (lane == 0) {
        ws[WS_GI + rA] = accA + b_ih[rA];
        ws[WS_GH + rA] = accB + b_hh[rA];
    }
}

// Fused logits: LANE-LOCAL GRU preamble (no LDS, no syncthreads) -> hv[] in
// registers, then the R8 hot loop verbatim (dual-row ILP, nt loads, online m/s).
__global__ void __launch_bounds__(256) logits_kernel(
        const float* __restrict__ hidden,
        const float* __restrict__ w_out,
        const float* __restrict__ b_out,
        float* __restrict__ ws,
        float* __restrict__ out) {
    __shared__ float sm[4], ssum[4];
    const int tid  = threadIdx.x;
    const int wid  = tid >> 6;
    const int lane = tid & 63;

    // Per-lane GRU nonlinearity for exactly the 16 h-values this lane needs:
    // coalesced float4 loads (adjacent lanes -> adjacent chunks), fast exp.
    float4 hv[4];
    #pragma unroll
    for (int k = 0; k < 4; ++k) {
        const int j = lane * 4 + k * 256;
        const float4 gir = *(const float4*)(ws + WS_GI + j);
        const float4 giz = *(const float4*)(ws + WS_GI + H + j);
        const float4 gin = *(const float4*)(ws + WS_GI + 2 * H + j);
        const float4 ghr = *(const float4*)(ws + WS_GH + j);
        const float4 ghz = *(const float4*)(ws + WS_GH + H + j);
        const float4 ghn = *(const float4*)(ws + WS_GH + 2 * H + j);
        const float4 h4  = *(const float4*)(hidden + j);
        float4 o;
        {
            const float r = 1.f / (1.f + __expf(-(gir.x + ghr.x)));
            const float z = 1.f / (1.f + __expf(-(giz.x + ghz.x)));
            const float e2 = __expf(2.f * (gin.x + r * ghn.x));
            o.x = (1.f - z) * (1.f - 2.f / (e2 + 1.f)) + z * h4.x;
        }
        {
            const float r = 1.f / (1.f + __expf(-(gir.y + ghr.y)));
            const float z = 1.f / (1.f + __expf(-(giz.y + ghz.y)));
            const float e2 = __expf(2.f * (gin.y + r * ghn.y));
            o.y = (1.f - z) * (1.f - 2.f / (e2 + 1.f)) + z * h4.y;
        }
        {
            const float r = 1.f / (1.f + __expf(-(gir.z + ghr.z)));
            const float z = 1.f / (1.f + __expf(-(giz.z + ghz.z)));
            const float e2 = __expf(2.f * (gin.z + r * ghn.z));
            o.z = (1.f - z) * (1.f - 2.f / (e2 + 1.f)) + z * h4.z;
        }
        {
            const float r = 1.f / (1.f + __expf(-(gir.w + ghr.w)));
            const float z = 1.f / (1.f + __expf(-(giz.w + ghz.w)));
            const float e2 = __expf(2.f * (gin.w + r * ghn.w));
            o.w = (1.f - z) * (1.f - 2.f / (e2 + 1.f)) + z * h4.w;
        }
        hv[k] = o;
    }

    // Second output: block 0 / wave 0 collectively holds all 1024 h values.
    if (blockIdx.x == 0 && wid == 0) {
        #pragma unroll
        for (int k = 0; k < 4; ++k)
            *(float4*)(out + V + lane * 4 + k * 256) = hv[k];
    }

    // Hot loop (R8 verbatim): each wave 16 rows at stride nwaves, 8 pairs.
    const int base   = blockIdx.x * 4 + wid;
    const int nwaves = NBLK_LOGITS * 4;            // 8000
    float m = -1e30f, s = 0.f;
    #pragma unroll
    for (int t = 0; t < 16; t += 2) {
        const int rowA = base + t * nwaves;
        const int rowB = base + (t + 1) * nwaves;
        const float* wrA = w_out + (size_t)rowA * H;
        const float* wrB = w_out + (size_t)rowB * H;
        const float bA = b_out[rowA];
        const float bB = b_out[rowB];
        float accA = 0.f, accB = 0.f;
        #pragma unroll
        for (int k = 0; k < 4; ++k) {
            const int j = lane * 4 + k * 256;
            f32x4 wa = __builtin_nontemporal_load((const f32x4*)(wrA + j));
            f32x4 wb = __builtin_nontemporal_load((const f32x4*)(wrB + j));
            accA += wa.x * hv[k].x + wa.y * hv[k].y + wa.z * hv[k].z + wa.w * hv[k].w;
            accB += wb.x * hv[k].x + wb.y * hv[k].y + wb.z * hv[k].z + wb.w * hv[k].w;
        }
        #pragma unroll
        for (int d = 32; d >= 1; d >>= 1) {        // interleaved dual reduce
            accA += __shfl_xor(accA, d);
            accB += __shfl_xor(accB, d);
        }
        accA += bA;
        accB += bB;
        if (lane == 0) { out[rowA] = accA; out[rowB] = accB; }
        float nm = fmaxf(m, accA);
        s = s * __expf(m - nm) + __expf(accA - nm);
        m = nm;
        nm = fmaxf(m, accB);
        s = s * __expf(m - nm) + __expf(accB - nm);
        m = nm;
    }

    if (lane == 0) { sm[wid] = m; ssum[wid] = s; }
    __syncthreads();
    if (tid == 0) {
        float M = sm[0], S = ssum[0];
        #pragma unroll
        for (int w = 1; w < 4; ++w) online_combine(M, S, sm[w], ssum[w]);
        ws[WS_PART + 2 * blockIdx.x]     = M;
        ws[WS_PART + 2 * blockIdx.x + 1] = S;
    }
}

// Fused final+write: each block redundantly combines 2000 partials (16 KB,
// L2-resident) then normalizes its slice in place. 125 blocks x 256 x float4.
__global__ void smax_write(float* __restrict__ out, const float* __restrict__ ws) {
    const int tid  = threadIdx.x;
    const int wid  = tid >> 6;
    const int lane = tid & 63;
    __shared__ float sm[4], ssum[4];
    __shared__ float c_sh;

    float m = -1e30f, s = 0.f;
    for (int i = tid; i < NBLK_LOGITS; i += 256) {
        online_combine(m, s, ws[WS_PART + 2 * i], ws[WS_PART + 2 * i + 1]);
    }
    #pragma unroll
    for (int d = 1; d < 64; d <<= 1) {
        const float om = __shfl_xor(m, d);
        const float os = __shfl_xor(s, d);
        online_combine(m, s, om, os);
    }
    if (lane == 0) { sm[wid] = m; ssum[wid] = s; }
    __syncthreads();
    if (tid == 0) {
        float M = sm[0], S = ssum[0];
        #pragma unroll
        for (int w = 1; w < 4; ++w) online_combine(M, S, sm[w], ssum[w]);
        c_sh = M + logf(S);
    }
    __syncthreads();
    const float c = c_sh;

    const int i = (blockIdx.x * 256 + tid) * 4;
    float4 v = *(float4*)(out + i);
    v.x -= c; v.y -= c; v.z -= c; v.w -= c;
    *(float4*)(out + i) = v;
}

extern "C" void kernel_launch(void* const* d_in, const int* in_sizes, int n_in,
                              void* d_out, int out_size, void* d_ws, size_t ws_size,
                              hipStream_t stream) {
    const int*   seq    = (const int*)d_in[0];
    const float* hidden = (const float*)d_in[1];
    const float* emb    = (const float*)d_in[2];
    const float* w_ih   = (const float*)d_in[3];
    const float* w_hh   = (const float*)d_in[4];
    const float* b_ih   = (const float*)d_in[5];
    const float* b_hh   = (const float*)d_in[6];
    const float* w_out  = (const float*)d_in[7];
    const float* b_out  = (const float*)d_in[8];
    float* out = (float*)d_out;
    float* ws  = (float*)d_ws;

    gates_kernel<<<NBLK_GATES, 256, 0, stream>>>(seq, hidden, emb, w_ih, w_hh,
                                                 b_ih, b_hh, ws);
    logits_kernel<<<NBLK_LOGITS, 256, 0, stream>>>(hidden, w_out, b_out, ws, out);
    smax_write<<<125, 256, 0, stream>>>(out, ws);
}

// Round 11
// 97.408 us; speedup vs baseline: 1.0155x; 1.0155x over previous
//
#include <hip/hip_runtime.h>

#define H 1024
#define V 128000
#define NBLK_GATES 768     // 768 blocks * 4 waves = 3072 wave-pairs (rows r and r+3072)
#define NBLK_LOGITS 2000   // 2000 blocks * 4 waves * 16 rows = 128000

typedef float f32x4 __attribute__((ext_vector_type(4)));

// ws float layout:
//  [0,3072)      gi  (r,z,n)
//  [3072,6144)   gh  (r,z,n)
//  [6144,10144)  2000 partial (m,s) pairs from logits blocks
#define WS_GI   0
#define WS_GH   3072
#define WS_PART 6144

__device__ __forceinline__ void online_combine(float& m, float& s, float om, float os) {
    const float M = fmaxf(m, om);
    s = s * __expf(m - M) + os * __expf(om - M);
    m = M;
}

// Dual-row gates: wave w handles row w (w_ih @ relu(emb[idx])) and row w+3072
// (w_hh @ h) with interleaved loads + interleaved shuffle reduce.
__global__ void __launch_bounds__(256) gates_kernel(
        const int* __restrict__ seq,
        const float* __restrict__ hidden,
        const float* __restrict__ emb,
        const float* __restrict__ w_ih,
        const float* __restrict__ w_hh,
        const float* __restrict__ b_ih,
        const float* __restrict__ b_hh,
        float* __restrict__ ws) {
    const int wid  = threadIdx.x >> 6;
    const int lane = threadIdx.x & 63;
    const int rA   = blockIdx.x * 4 + wid;       // 0..3071
    const int idx  = seq[0];

    const float* wrA = w_ih + (size_t)rA * H;
    const float* wrB = w_hh + (size_t)rA * H;
    const float* vA  = emb + (size_t)idx * H;
    const float* vB  = hidden;

    float accA = 0.f, accB = 0.f;
    #pragma unroll
    for (int k = 0; k < 4; ++k) {
        const int j = lane * 4 + k * 256;
        float4 wa = *(const float4*)(wrA + j);
        float4 wb = *(const float4*)(wrB + j);
        float4 va = *(const float4*)(vA + j);
        float4 vb = *(const float4*)(vB + j);
        va.x = fmaxf(va.x, 0.f); va.y = fmaxf(va.y, 0.f);
        va.z = fmaxf(va.z, 0.f); va.w = fmaxf(va.w, 0.f);
        accA += wa.x * va.x + wa.y * va.y + wa.z * va.z + wa.w * va.w;
        accB += wb.x * vb.x + wb.y * vb.y + wb.z * vb.z + wb.w * vb.w;
    }
    #pragma unroll
    for (int d = 32; d >= 1; d >>= 1) {
        accA += __shfl_xor(accA, d);
        accB += __shfl_xor(accB, d);
    }
    if (lane == 0) {
        ws[WS_GI + rA] = accA + b_ih[rA];
        ws[WS_GH + rA] = accB + b_hh[rA];
    }
}

// Fused: per-block redundant GRU nonlinearity (fast-exp) -> h_new in LDS,
// block 0 writes hidden output, then one wave per vocab row pair (dual-row ILP,
// nontemporal w_out loads) with online (m,s) tracking; one partial per block.
__global__ void __launch_bounds__(256) logits_kernel(
        const float* __restrict__ hidden,
        const float* __restrict__ w_out,
        const float* __restrict__ b_out,
        float* __restrict__ ws,
        float* __restrict__ out) {
    __shared__ float sh_h[H];
    __shared__ float sm[4], ssum[4];
    const int tid = threadIdx.x;

    // GRU nonlinearity, 4 elems/thread (fast exp; error budget ~0.27 abs)
    #pragma unroll
    for (int k = 0; k < 4; ++k) {
        const int i = tid + k * 256;
        const float gi_r = ws[WS_GI + i];
        const float gi_z = ws[WS_GI + H + i];
        const float gi_n = ws[WS_GI + 2 * H + i];
        const float gh_r = ws[WS_GH + i];
        const float gh_z = ws[WS_GH + H + i];
        const float gh_n = ws[WS_GH + 2 * H + i];
        const float r = 1.f / (1.f + __expf(-(gi_r + gh_r)));
        const float z = 1.f / (1.f + __expf(-(gi_z + gh_z)));
        const float a = gi_n + r * gh_n;
        const float e2 = __expf(2.f * a);
        const float n = 1.f - 2.f / (e2 + 1.f);   // tanh(a), exact at +/-inf
        const float h = hidden[i];
        sh_h[i] = (1.f - z) * n + z * h;
    }
    __syncthreads();

    if (blockIdx.x == 0) {   // second output: new hidden state
        #pragma unroll
        for (int k = 0; k < 4; ++k) {
            const int i = tid + k * 256;
            out[V + i] = sh_h[i];
        }
    }

    const int wid  = tid >> 6;
    const int lane = tid & 63;
    float4 hv[4];
    #pragma unroll
    for (int k = 0; k < 4; ++k) hv[k] = *(const float4*)(&sh_h[lane * 4 + k * 256]);

    // Each wave: 16 rows at stride nwaves, processed as 8 pairs (dual-row ILP).
    const int base   = blockIdx.x * 4 + wid;
    const int nwaves = NBLK_LOGITS * 4;            // 8000
    float m = -1e30f, s = 0.f;
    #pragma unroll
    for (int t = 0; t < 16; t += 2) {
        const int rowA = base + t * nwaves;
        const int rowB = base + (t + 1) * nwaves;
        const float* wrA = w_out + (size_t)rowA * H;
        const float* wrB = w_out + (size_t)rowB * H;
        const float bA = b_out[rowA];
        const float bB = b_out[rowB];
        float accA = 0.f, accB = 0.f;
        #pragma unroll
        for (int k = 0; k < 4; ++k) {
            const int j = lane * 4 + k * 256;
            f32x4 wa = __builtin_nontemporal_load((const f32x4*)(wrA + j));
            f32x4 wb = __builtin_nontemporal_load((const f32x4*)(wrB + j));
            accA += wa.x * hv[k].x + wa.y * hv[k].y + wa.z * hv[k].z + wa.w * hv[k].w;
            accB += wb.x * hv[k].x + wb.y * hv[k].y + wb.z * hv[k].z + wb.w * hv[k].w;
        }
        #pragma unroll
        for (int d = 32; d >= 1; d >>= 1) {        // interleaved dual reduce
            accA += __shfl_xor(accA, d);
            accB += __shfl_xor(accB, d);
        }
        accA += bA;
        accB += bB;
        if (lane == 0) { out[rowA] = accA; out[rowB] = accB; }
        float nm = fmaxf(m, accA);
        s = s * __expf(m - nm) + __expf(accA - nm);
        m = nm;
        nm = fmaxf(m, accB);
        s = s * __expf(m - nm) + __expf(accB - nm);
        m = nm;
    }

    if (lane == 0) { sm[wid] = m; ssum[wid] = s; }
    __syncthreads();
    if (tid == 0) {
        float M = sm[0], S = ssum[0];
        #pragma unroll
        for (int w = 1; w < 4; ++w) online_combine(M, S, sm[w], ssum[w]);
        ws[WS_PART + 2 * blockIdx.x]     = M;
        ws[WS_PART + 2 * blockIdx.x + 1] = S;
    }
}

// Fused final+write: each block redundantly combines 2000 partials (16 KB,
// L2-resident) then normalizes its slice in place. 125 blocks x 256 x float4.
__global__ void smax_write(float* __restrict__ out, const float* __restrict__ ws) {
    const int tid  = threadIdx.x;
    const int wid  = tid >> 6;
    const int lane = tid & 63;
    __shared__ float sm[4], ssum[4];
    __shared__ float c_sh;

    float m = -1e30f, s = 0.f;
    for (int i = tid; i < NBLK_LOGITS; i += 256) {
        online_combine(m, s, ws[WS_PART + 2 * i], ws[WS_PART + 2 * i + 1]);
    }
    #pragma unroll
    for (int d = 1; d < 64; d <<= 1) {
        const float om = __shfl_xor(m, d);
        const float os = __shfl_xor(s, d);
        online_combine(m, s, om, os);
    }
    if (lane == 0) { sm[wid] = m; ssum[wid] = s; }
    __syncthreads();
    if (tid == 0) {
        float M = sm[0], S = ssum[0];
        #pragma unroll
        for (int w = 1; w < 4; ++w) online_combine(M, S, sm[w], ssum[w]);
        c_sh = M + logf(S);
    }
    __syncthreads();
    const float c = c_sh;

    const int i = (blockIdx.x * 256 + tid) * 4;
    float4 v = *(float4*)(out + i);
    v.x -= c; v.y -= c; v.z -= c; v.w -= c;
    *(float4*)(out + i) = v;
}

extern "C" void kernel_launch(void* const* d_in, const int* in_sizes, int n_in,
                              void* d_out, int out_size, void* d_ws, size_t ws_size,
                              hipStream_t stream) {
    const int*   seq    = (const int*)d_in[0];
    const float* hidden = (const float*)d_in[1];
    const float* emb    = (const float*)d_in[2];
    const float* w_ih   = (const float*)d_in[3];
    const float* w_hh   = (const float*)d_in[4];
    const float* b_ih   = (const float*)d_in[5];
    const float* b_hh   = (const float*)d_in[6];
    const float* w_out  = (const float*)d_in[7];
    const float* b_out  = (const float*)d_in[8];
    float* out = (float*)d_out;
    float* ws  = (float*)d_ws;

    gates_kernel<<<NBLK_GATES, 256, 0, stream>>>(seq, hidden, emb, w_ih, w_hh,
                                                 b_ih, b_hh, ws);
    logits_kernel<<<NBLK_LOGITS, 256, 0, stream>>>(hidden, w_out, b_out, ws, out);
    smax_write<<<125, 256, 0, stream>>>(out, ws);
}